// Round 13
// baseline (195.971 us; speedup 1.0000x reference)
//
#include <hip/hip_runtime.h>
#include <hip/hip_bf16.h>
#include <cmath>

#define TEXTD 500
#define GNN_DIM 128
#define DEGP(v) ((v) << 5)   // one counter per 128B line

typedef __attribute__((ext_vector_type(8))) short bf16x8;
typedef __attribute__((ext_vector_type(4))) float f32x4;

__device__ __forceinline__ float bf2f(unsigned short u) {
    union { unsigned int i; float f; } cv;
    cv.i = ((unsigned int)u) << 16;
    return cv.f;
}
__device__ __forceinline__ unsigned short f2b(float x) {
    __hip_bfloat16 b = __float2bfloat16(x);
    return *reinterpret_cast<unsigned short*>(&b);
}
__device__ __forceinline__ float u2f(unsigned int u) {
    union { unsigned int i; float f; } cv; cv.i = u; return cv.f;
}
__device__ __forceinline__ bf16x8 cvt8(const float* p) {
    float4 u = *(const float4*)p;
    float4 v = *(const float4*)(p + 4);
    bf16x8 f;
    f[0] = (short)f2b(u.x); f[1] = (short)f2b(u.y);
    f[2] = (short)f2b(u.z); f[3] = (short)f2b(u.w);
    f[4] = (short)f2b(v.x); f[5] = (short)f2b(v.y);
    f[6] = (short)f2b(v.z); f[7] = (short)f2b(v.w);
    return f;
}

// ---------------- setup: zero padded deg counters + weight conversion ----------------
__global__ __launch_bounds__(256) void setup_kernel(
    int* __restrict__ deg, int N, int NB,
    const float* __restrict__ fc1_w, const float* __restrict__ sc_w,
    const float* __restrict__ W1, const float* __restrict__ W2,
    unsigned short* __restrict__ w1cat, unsigned short* __restrict__ w1g,
    unsigned short* __restrict__ w2t)
{
    if ((int)blockIdx.x < NB) {
        int v = blockIdx.x * 256 + threadIdx.x;
        if (v < N) deg[DEGP(v)] = 0;
        return;
    }
    int idx = (blockIdx.x - NB) * 256 + threadIdx.x;
    if (idx < 144 * 512) {
        int n = idx >> 9, k = idx & 511;
        float v = 0.f;
        if (k < TEXTD) v = (n < 128) ? fc1_w[k * 128 + n] : sc_w[k * 16 + (n - 128)];
        w1cat[idx] = f2b(v);
    } else if (idx < 144 * 512 + 128 * 128) {
        int j = idx - 144 * 512;
        int n = j >> 7, k = j & 127;
        w1g[j] = f2b(W1[k * 128 + n]);
    } else if (idx < 144 * 512 + 128 * 128 + 16 * 128) {
        int j = idx - (144 * 512 + 128 * 128);
        int n = j >> 7, k = j & 127;
        w2t[j] = f2b(W2[k * 16 + n]);
    }
}

// ---------------- GEMM1: text[fp32, Mx500] x w1cat[144x512]^T -> t1(relu+b), tsc(+b) ----------------
__global__ __launch_bounds__(256) void gemm_text_kernel(
    const float* __restrict__ text, const short* __restrict__ B,
    const float* __restrict__ fc1_b, const float* __restrict__ sc_b,
    float* __restrict__ t1, float* __restrict__ tsc, int M)
{
    const int tid = threadIdx.x;
    const int wave = tid >> 6, lane = tid & 63;
    const int q = lane >> 4, col = lane & 15;
    const int mb = blockIdx.x * 64 + wave * 16;
    const int arow = min(mb + col, M - 1);
    const float* ap = text + (size_t)arow * TEXTD + q * 8;

    bf16x8 afrag[16];
    #pragma unroll
    for (int ks = 0; ks < 15; ks++) afrag[ks] = cvt8(ap + ks * 32);
    {   // ks = 15: K 480..511, zero-pad past 500
        bf16x8 f;
        int k0 = 480 + q * 8;
        #pragma unroll
        for (int e = 0; e < 8; e++) {
            int k = k0 + e;
            f[e] = (short)((k < TEXTD) ? f2b(text[(size_t)arow * TEXTD + k]) : 0);
        }
        afrag[15] = f;
    }

    for (int nb = 0; nb < 9; nb++) {
        const short* bp = B + (size_t)(nb * 16 + col) * 512 + q * 8;
        f32x4 acc = {0.f, 0.f, 0.f, 0.f};
        #pragma unroll
        for (int ks = 0; ks < 16; ks++)
            acc = __builtin_amdgcn_mfma_f32_16x16x32_bf16(afrag[ks], *(const bf16x8*)(bp + ks * 32), acc, 0, 0, 0);
        #pragma unroll
        for (int i = 0; i < 4; i++) {
            int row = mb + q * 4 + i;
            if (row < M) {
                if (nb < 8) t1[(size_t)row * 128 + nb * 16 + col] = fmaxf(acc[i] + fc1_b[nb * 16 + col], 0.f);
                else        tsc[(size_t)row * 16 + col] = acc[i] + sc_b[col];
            }
        }
    }
}

// ---------------- text tail: fc2/fc3/fc4 + shortcut (8 rows/block, high grid parallelism) ----------------
__global__ __launch_bounds__(128) void text_tail_kernel(
    const float* __restrict__ t1g, const float* __restrict__ tsc,
    const float* __restrict__ fc2_w, const float* __restrict__ fc2_b,
    const float* __restrict__ fc3_w, const float* __restrict__ fc3_b,
    const float* __restrict__ fc4_w, const float* __restrict__ fc4_b,
    float* __restrict__ text_out, int M)
{
    __shared__ float t1[8][128];
    __shared__ float t2[8][64];
    __shared__ float t3[8][16];
    const int tid = threadIdx.x;
    const int m0 = blockIdx.x * 8;

    for (int r = 0; r < 8; r++) {
        int row = m0 + r;
        t1[r][tid] = (row < M) ? t1g[(size_t)row * 128 + tid] : 0.f;
    }
    __syncthreads();

    const int r2 = tid >> 6, c2 = tid & 63;
    for (int rb = 0; rb < 4; rb++) {
        int row = rb * 2 + r2;
        float a2 = fc2_b[c2];
        for (int k = 0; k < 128; k++) a2 = fmaf(t1[row][k], fc2_w[k * 64 + c2], a2);
        t2[row][c2] = fmaxf(a2, 0.f);
    }
    __syncthreads();

    const int rs = tid >> 4, cs = tid & 15;
    float a3 = fc3_b[cs];
    for (int k = 0; k < 64; k++) a3 = fmaf(t2[rs][k], fc3_w[k * 16 + cs], a3);
    t3[rs][cs] = fmaxf(a3, 0.f);
    __syncthreads();

    float a4 = fc4_b[cs];
    #pragma unroll
    for (int k = 0; k < 16; k++) a4 = fmaf(t3[rs][k], fc4_w[k * 16 + cs], a4);
    int row = m0 + rs;
    if (row < M) text_out[(size_t)row * 16 + cs] = a4 + tsc[(size_t)row * 16 + cs];
}

// ---------------- GEMM2: x[fp32, Nx128] @ W1 -> h1 bf16; fused a_s1/a_d1 epilogue ----------------
__global__ __launch_bounds__(256) void gemm_h1_kernel(
    const float* __restrict__ x, const short* __restrict__ B,
    const float* __restrict__ as1w, const float* __restrict__ ad1w,
    unsigned short* __restrict__ h1, float* __restrict__ a_s, float* __restrict__ a_d, int N)
{
    const int tid = threadIdx.x;
    const int wave = tid >> 6, lane = tid & 63;
    const int q = lane >> 4, col = lane & 15;
    const int mb = blockIdx.x * 64 + wave * 16;
    const int arow = min(mb + col, N - 1);
    const float* ap = x + (size_t)arow * 128 + q * 8;

    bf16x8 afrag[4];
    #pragma unroll
    for (int ks = 0; ks < 4; ks++) afrag[ks] = cvt8(ap + ks * 32);

    float ps0[4] = {0,0,0,0}, ps1[4] = {0,0,0,0};
    float pd0[4] = {0,0,0,0}, pd1[4] = {0,0,0,0};

    #pragma unroll
    for (int nb = 0; nb < 8; nb++) {
        const short* bp = B + (size_t)(nb * 16 + col) * 128 + q * 8;
        f32x4 acc = {0.f, 0.f, 0.f, 0.f};
        #pragma unroll
        for (int ks = 0; ks < 4; ks++)
            acc = __builtin_amdgcn_mfma_f32_16x16x32_bf16(afrag[ks], *(const bf16x8*)(bp + ks * 32), acc, 0, 0, 0);
        const int j = nb * 16 + col;
        const float asj = as1w[j], adj = ad1w[j];
        #pragma unroll
        for (int i = 0; i < 4; i++) {
            int row = mb + q * 4 + i;
            if (row < N) h1[(size_t)row * 128 + j] = f2b(acc[i]);
            if (nb < 4) { ps0[i] = fmaf(acc[i], asj, ps0[i]); pd0[i] = fmaf(acc[i], adj, pd0[i]); }
            else        { ps1[i] = fmaf(acc[i], asj, ps1[i]); pd1[i] = fmaf(acc[i], adj, pd1[i]); }
        }
    }
    #pragma unroll
    for (int i = 0; i < 4; i++) {
        float v0 = ps0[i], v1 = ps1[i], w0 = pd0[i], w1 = pd1[i];
        #pragma unroll
        for (int off = 1; off < 16; off <<= 1) {
            v0 += __shfl_xor(v0, off, 16);
            v1 += __shfl_xor(v1, off, 16);
            w0 += __shfl_xor(w0, off, 16);
            w1 += __shfl_xor(w1, off, 16);
        }
        int row = mb + q * 4 + i;
        if (col == 0 && row < N) {
            a_s[2 * row] = v0; a_s[2 * row + 1] = v1;
            a_d[2 * row] = w0; a_d[2 * row + 1] = w1;
        }
    }
}

// ---------------- CSR build ----------------
__global__ __launch_bounds__(256) void deg_hist_kernel(
    const int* __restrict__ edst, int* __restrict__ deg, int* __restrict__ rank, int E)
{
    const int base = blockIdx.x * 1024 + threadIdx.x;
    int e0 = base;
    int e1 = base + 256;
    int e2 = base + 512;
    int e3 = base + 768;
    int d0 = (e0 < E) ? edst[e0] : -1;
    int d1 = (e1 < E) ? edst[e1] : -1;
    int d2 = (e2 < E) ? edst[e2] : -1;
    int d3 = (e3 < E) ? edst[e3] : -1;
    int r0 = (d0 >= 0) ? atomicAdd(&deg[DEGP(d0)], 1) : 0;
    int r1 = (d1 >= 0) ? atomicAdd(&deg[DEGP(d1)], 1) : 0;
    int r2 = (d2 >= 0) ? atomicAdd(&deg[DEGP(d2)], 1) : 0;
    int r3 = (d3 >= 0) ? atomicAdd(&deg[DEGP(d3)], 1) : 0;
    if (d0 >= 0) rank[e0] = r0;
    if (d1 >= 0) rank[e1] = r1;
    if (d2 >= 0) rank[e2] = r2;
    if (d3 >= 0) rank[e3] = r3;
}

// phase 1: per-256-tile sums of (deg[i]+1)
__global__ __launch_bounds__(256) void part_kernel(
    const int* __restrict__ deg, int* __restrict__ bsum, int N)
{
    const int tid = threadIdx.x;
    int i = blockIdx.x * 256 + tid;
    int d = (i < N) ? deg[DEGP(i)] + 1 : 0;
    #pragma unroll
    for (int off = 32; off > 0; off >>= 1) d += __shfl_down(d, off, 64);
    __shared__ int wsum[4];
    if ((tid & 63) == 0) wsum[tid >> 6] = d;
    __syncthreads();
    if (tid == 0) bsum[blockIdx.x] = wsum[0] + wsum[1] + wsum[2] + wsum[3];
}

// phase 2 (fused): each block scans bsum in LDS, then in-block element scan -> rowptr
__global__ __launch_bounds__(256) void rowptr_kernel(
    const int* __restrict__ deg, const int* __restrict__ bsum,
    int* __restrict__ rowptr, int N, int NB)
{
    __shared__ int bsc[256];
    __shared__ int sc[256];
    const int tid = threadIdx.x;

    int bv = (tid < NB) ? bsum[tid] : 0;
    bsc[tid] = bv;
    for (int off = 1; off < 256; off <<= 1) {
        __syncthreads();
        int t = (tid >= off) ? bsc[tid - off] : 0;
        __syncthreads();
        bsc[tid] += t;
    }
    __syncthreads();
    const int base = (blockIdx.x == 0) ? 0 : bsc[blockIdx.x - 1];

    const int i = blockIdx.x * 256 + tid;
    int d = (i < N) ? deg[DEGP(i)] + 1 : 0;
    sc[tid] = d;
    for (int off = 1; off < 256; off <<= 1) {
        __syncthreads();
        int t = (tid >= off) ? sc[tid - off] : 0;
        __syncthreads();
        sc[tid] += t;
    }
    __syncthreads();
    int incl = sc[tid];
    if (i < N) rowptr[i] = base + incl - d;
    if (i == N - 1) rowptr[N] = base + incl;
}

__device__ __forceinline__ float edge_w(float e) {
    return __expf(e > 0.f ? e : 0.2f * e);
}

// fill CSR slots: single 8B store per edge {src, bf16 w0 | w1<<16}; no atomics
__global__ __launch_bounds__(256) void fillw_kernel(
    const int* __restrict__ esrc, const int* __restrict__ edst,
    const int* __restrict__ rank, const int* __restrict__ rowptr,
    uint2* __restrict__ eslot,
    const float* __restrict__ a_s, const float* __restrict__ a_d, int E, int N)
{
    int e = blockIdx.x * 256 + threadIdx.x;
    if (e < E) {
        int src = esrc[e], dst = edst[e];
        int pos = rowptr[dst] + 1 + rank[e];
        float2 as = *(const float2*)(a_s + 2 * src);
        float2 ad = *(const float2*)(a_d + 2 * dst);
        unsigned int w0 = f2b(edge_w(as.x + ad.x));
        unsigned int w1 = f2b(edge_w(as.y + ad.y));
        uint2 o; o.x = (unsigned int)src; o.y = (w1 << 16) | w0;
        eslot[pos] = o;
    } else if (e < E + N) {
        int v = e - E;
        float2 as = *(const float2*)(a_s + 2 * v);
        float2 ad = *(const float2*)(a_d + 2 * v);
        unsigned int w0 = f2b(edge_w(as.x + ad.x));
        unsigned int w1 = f2b(edge_w(as.y + ad.y));
        uint2 o; o.x = (unsigned int)v; o.y = (w1 << 16) | w0;
        eslot[rowptr[v]] = o;
    }
}

// ---------------- layer-1 gather: 1 WAVE/node (4 nodes/block), 2 slots x 32 lanes(x4 dims) ----------------
template<int B>
__device__ __forceinline__ void gat1_batch(
    int i0, int end, int endm1, int wsh,
    const uint2* __restrict__ eslot, const uint2* __restrict__ h1u, unsigned int dp,
    float& a0, float& a1, float& a2, float& a3, float& den)
{
    int ics[B];
    uint2 sl[B];
    float wv[B];
    uint2 hv[B];
    #pragma unroll
    for (int k = 0; k < B; k++) ics[k] = min(i0 + 2 * k, endm1);
    #pragma unroll
    for (int k = 0; k < B; k++) sl[k] = eslot[ics[k]];
    #pragma unroll
    for (int k = 0; k < B; k++) {
        float w = u2f((sl[k].y << wsh) & 0xffff0000u);
        wv[k] = (i0 + 2 * k < end) ? w : 0.f;
    }
    #pragma unroll
    for (int k = 0; k < B; k++) hv[k] = h1u[(sl[k].x << 5) | dp];
    #pragma unroll
    for (int k = 0; k < B; k++) {
        float w = wv[k];
        den += w;
        a0 = fmaf(w, u2f(hv[k].x << 16),          a0);
        a1 = fmaf(w, u2f(hv[k].x & 0xffff0000u),  a1);
        a2 = fmaf(w, u2f(hv[k].y << 16),          a2);
        a3 = fmaf(w, u2f(hv[k].y & 0xffff0000u),  a3);
    }
}

__global__ __launch_bounds__(256) void gat1_gather_kernel(
    const int* __restrict__ rowptr, const uint2* __restrict__ eslot,
    const uint2* __restrict__ h1u,
    const float* __restrict__ b1, uint2* __restrict__ g1b, int N)
{
    const int v = blockIdx.x * 4 + (threadIdx.x >> 6);
    if (v >= N) return;
    const int lane = threadIdx.x & 63;
    const int slot = lane >> 5;
    const unsigned int dp = lane & 31;
    const int head = dp >> 4;
    const int wsh = head ? 0 : 16;
    const int beg = rowptr[v], end = rowptr[v + 1];
    const int deg = end - beg;
    const int endm1 = end - 1;
    const int i0 = beg + slot;

    float a0 = 0.f, a1 = 0.f, a2 = 0.f, a3 = 0.f, den = 0.f;

    if (deg <= 8) {
        gat1_batch<4>(i0, end, endm1, wsh, eslot, h1u, dp, a0, a1, a2, a3, den);
    } else {
        gat1_batch<8>(i0, end, endm1, wsh, eslot, h1u, dp, a0, a1, a2, a3, den);
        for (int base = i0 + 16; base < end; base += 8)
            gat1_batch<4>(base, end, endm1, wsh, eslot, h1u, dp, a0, a1, a2, a3, den);
    }

    a0 += __shfl_xor(a0, 32, 64);
    a1 += __shfl_xor(a1, 32, 64);
    a2 += __shfl_xor(a2, 32, 64);
    a3 += __shfl_xor(a3, 32, 64);
    den += __shfl_xor(den, 32, 64);

    if (lane < 32) {
        float inv = 1.f / (den + 1e-16f);
        float4 bv = *(const float4*)(b1 + 4 * dp);
        float o0 = fmaxf(fmaf(a0, inv, bv.x), 0.f);
        float o1 = fmaxf(fmaf(a1, inv, bv.y), 0.f);
        float o2 = fmaxf(fmaf(a2, inv, bv.z), 0.f);
        float o3 = fmaxf(fmaf(a3, inv, bv.w), 0.f);
        uint2 o;
        o.x = ((unsigned int)f2b(o1) << 16) | f2b(o0);
        o.y = ((unsigned int)f2b(o3) << 16) | f2b(o2);
        g1b[((unsigned int)v << 5) | dp] = o;
    }
}

// ---------------- gat2 projection (MFMA): h2 = g1b @ W2; fused a_s2/a_d2 ----------------
__global__ __launch_bounds__(256) void gat2_proj_kernel(
    const unsigned short* __restrict__ g1b, const short* __restrict__ w2t,
    const float* __restrict__ as2w, const float* __restrict__ ad2w,
    float* __restrict__ h2, float* __restrict__ a_s2, float* __restrict__ a_d2, int N)
{
    const int tid = threadIdx.x;
    const int wave = tid >> 6, lane = tid & 63;
    const int q = lane >> 4, col = lane & 15;
    const int mb = blockIdx.x * 64 + wave * 16;
    const int arow = min(mb + col, N - 1);
    const short* ap = (const short*)g1b + (size_t)arow * 128 + q * 8;
    const short* bp = w2t + (size_t)col * 128 + q * 8;

    f32x4 acc = {0.f, 0.f, 0.f, 0.f};
    #pragma unroll
    for (int ks = 0; ks < 4; ks++)
        acc = __builtin_amdgcn_mfma_f32_16x16x32_bf16(
            *(const bf16x8*)(ap + ks * 32), *(const bf16x8*)(bp + ks * 32), acc, 0, 0, 0);

    const float asj = as2w[col], adj = ad2w[col];
    #pragma unroll
    for (int i = 0; i < 4; i++) {
        int row = mb + q * 4 + i;
        float ps = acc[i] * asj, pd = acc[i] * adj;
        #pragma unroll
        for (int off = 1; off < 16; off <<= 1) {
            ps += __shfl_xor(ps, off, 16);
            pd += __shfl_xor(pd, off, 16);
        }
        if (row < N) {
            h2[(size_t)row * 16 + col] = acc[i];
            if (col == 0) { a_s2[row] = ps; a_d2[row] = pd; }
        }
    }
}

// ---------------- fused layer-2 gather + head (4 masked nodes/block) ----------------
__global__ __launch_bounds__(256) void gat2_final_kernel(
    const int* __restrict__ rowptr, const uint2* __restrict__ eslot,
    const float* __restrict__ h2,
    const float* __restrict__ a_s2, const float* __restrict__ a_d2,
    const float* __restrict__ b2, const int* __restrict__ mask,
    const float* __restrict__ text_out,
    const float* __restrict__ fcf_w, const float* __restrict__ fcf_b,
    float* __restrict__ out, int M)
{
    const int tid = threadIdx.x;
    const int m = blockIdx.x * 4 + (tid >> 6);
    if (m >= M) return;
    const int lane = tid & 63, slot = lane >> 4, c = lane & 15;
    const int v = mask[m];
    const float adv = a_d2[v];
    const int beg = rowptr[v], end = rowptr[v + 1];
    const int i0 = beg + slot;

    float acc = 0.f, den = 0.f;
    unsigned int idxs[8];
    float msk[8], as_[8], hval[8];
    #pragma unroll
    for (int k = 0; k < 8; k++) {
        int i = i0 + 4 * k;
        int ic = min(i, end - 1);
        idxs[k] = eslot[ic].x;
        msk[k] = (i < end) ? 1.f : 0.f;
    }
    #pragma unroll
    for (int k = 0; k < 8; k++) as_[k] = a_s2[idxs[k]];
    #pragma unroll
    for (int k = 0; k < 8; k++) hval[k] = h2[(idxs[k] << 4) | (unsigned)c];
    #pragma unroll
    for (int k = 0; k < 8; k++) {
        float e = as_[k] + adv;
        float w = msk[k] * __expf(e > 0.f ? e : 0.2f * e);
        den += w;
        acc = fmaf(w, hval[k], acc);
    }
    for (int i = i0 + 32; i < end; i += 4) {
        unsigned int src = eslot[i].x;
        float e = a_s2[src] + adv;
        float w = __expf(e > 0.f ? e : 0.2f * e);
        den += w;
        acc = fmaf(w, h2[(src << 4) | (unsigned)c], acc);
    }

    acc += __shfl_xor(acc, 16, 64);
    acc += __shfl_xor(acc, 32, 64);
    den += __shfl_xor(den, 16, 64);
    den += __shfl_xor(den, 32, 64);

    if (slot == 0) {
        float gval = acc / (den + 1e-16f) + b2[c];
        float tval = text_out[(size_t)m * 16 + c];

        float logit = fcf_b[c];
        #pragma unroll
        for (int k = 0; k < 16; k++) {
            logit = fmaf(__shfl(tval, k, 16), fcf_w[k * 16 + c], logit);
            logit = fmaf(__shfl(gval, k, 16), fcf_w[(16 + k) * 16 + c], logit);
        }
        float mx = logit;
        #pragma unroll
        for (int off = 8; off > 0; off >>= 1) mx = fmaxf(mx, __shfl_xor(mx, off, 16));
        float se = expf(logit - mx);
        #pragma unroll
        for (int off = 8; off > 0; off >>= 1) se += __shfl_xor(se, off, 16);
        out[(size_t)m * 16 + c] = logit - mx - logf(se);
    }
}

extern "C" void kernel_launch(void* const* d_in, const int* in_sizes, int n_in,
                              void* d_out, int out_size, void* d_ws, size_t ws_size,
                              hipStream_t stream)
{
    const float* text  = (const float*)d_in[0];
    const float* x     = (const float*)d_in[1];
    const int*   ei    = (const int*)  d_in[2];
    const int*   mask  = (const int*)  d_in[3];
    const float* fc1_w = (const float*)d_in[4];  const float* fc1_b = (const float*)d_in[5];
    const float* fc2_w = (const float*)d_in[6];  const float* fc2_b = (const float*)d_in[7];
    const float* fc3_w = (const float*)d_in[8];  const float* fc3_b = (const float*)d_in[9];
    const float* fc4_w = (const float*)d_in[10]; const float* fc4_b = (const float*)d_in[11];
    const float* sc_w  = (const float*)d_in[12]; const float* sc_b  = (const float*)d_in[13];
    const float* W1    = (const float*)d_in[14];
    const float* as1w  = (const float*)d_in[15]; const float* ad1w  = (const float*)d_in[16];
    const float* b1    = (const float*)d_in[17];
    const float* W2    = (const float*)d_in[18];
    const float* as2w  = (const float*)d_in[19]; const float* ad2w  = (const float*)d_in[20];
    const float* b2    = (const float*)d_in[21];
    const float* fcf_w = (const float*)d_in[22]; const float* fcf_b = (const float*)d_in[23];

    const int M  = in_sizes[3];
    const int N  = in_sizes[1] / GNN_DIM;
    const int E  = in_sizes[2] / 2;
    const int EP = E + N;
    const int* esrc = ei;
    const int* edst = ei + E;

    const int Mp = ((M + 63) / 64) * 64;
    const int Np = ((N + 63) / 64) * 64;
    const int NB = (N + 255) / 256;        // <= 256

    float* ws = (float*)d_ws;
    size_t off = 0;
    auto alloc = [&](size_t n) { float* p = ws + off; off += (n + 63) & ~size_t(63); return p; };

    unsigned short* h1    = (unsigned short*)alloc((size_t)Np * 64);   // bf16 [Np x 128]
    unsigned int*   g1b   = (unsigned int*)  alloc((size_t)N * 64);    // bf16 [N x 128] packed
    unsigned short* w1cat = (unsigned short*)alloc(144 * 256);         // bf16 [144 x 512]
    unsigned short* w1g   = (unsigned short*)alloc(128 * 64);          // bf16 [128 x 128]
    unsigned short* w2t   = (unsigned short*)alloc(16 * 64);           // bf16 [16 x 128]
    float* t1       = alloc((size_t)M * 128);
    float* tsc      = alloc((size_t)M * 16);
    float* a_s1     = alloc((size_t)2 * N);
    float* a_d1     = alloc((size_t)2 * N);
    float* h2       = alloc((size_t)N * 16);
    float* a_s2     = alloc(N);
    float* a_d2     = alloc(N);
    float* text_out = alloc((size_t)M * 16);
    uint2* eslot    = (uint2*)alloc((size_t)2 * EP);   // {src, bf16w0|bf16w1<<16}
    int* deg        = (int*)alloc((size_t)N * 32);     // padded: 1 counter / 128B
    int* rank       = (int*)alloc(E);
    int* rowptr     = (int*)alloc(N + 1);
    int* bsum       = (int*)alloc(256);

    const int convBlocks = (144 * 512 + 128 * 128 + 16 * 128 + 255) / 256;

    // --- setup: zero counters + weights to bf16 (one kernel) ---
    setup_kernel<<<NB + convBlocks, 256, 0, stream>>>(
        deg, N, NB, fc1_w, sc_w, W1, W2, w1cat, w1g, w2t);

    // --- CSR: histogram(+rank) -> part sums -> rowptr (inline bsum scan) ---
    deg_hist_kernel<<<(E + 1023) / 1024, 256, 0, stream>>>(edst, deg, rank, E);
    part_kernel<<<NB, 256, 0, stream>>>(deg, bsum, N);
    rowptr_kernel<<<NB, 256, 0, stream>>>(deg, bsum, rowptr, N, NB);

    // --- GAT1 projection (produces a_s1/a_d1 for weight fill) ---
    gemm_h1_kernel<<<Np / 64, 256, 0, stream>>>(
        x, (const short*)w1g, as1w, ad1w, h1, a_s1, a_d1, N);

    // --- CSR fill: single 8B slot per edge, no atomics ---
    fillw_kernel<<<(E + N + 255) / 256, 256, 0, stream>>>(
        esrc, edst, rank, rowptr, eslot, a_s1, a_d1, E, N);

    // --- text branch (split: GEMM-shaped + tail-shaped grids) ---
    gemm_text_kernel<<<Mp / 64, 256, 0, stream>>>(
        text, (const short*)w1cat, fc1_b, sc_b, t1, tsc, M);
    text_tail_kernel<<<(M + 7) / 8, 128, 0, stream>>>(
        t1, tsc, fc2_w, fc2_b, fc3_w, fc3_b, fc4_w, fc4_b, text_out, M);

    // --- GNN aggregation / second layer ---
    gat1_gather_kernel<<<(N + 3) / 4, 256, 0, stream>>>(
        rowptr, eslot, (const uint2*)h1, b1, (uint2*)g1b, N);

    gat2_proj_kernel<<<Np / 64, 256, 0, stream>>>(
        (const unsigned short*)g1b, (const short*)w2t, as2w, ad2w, h2, a_s2, a_d2, N);

    // --- fused layer-2 gather + head ---
    gat2_final_kernel<<<(M + 3) / 4, 256, 0, stream>>>(
        rowptr, eslot, h2, a_s2, a_d2, b2, mask, text_out, fcf_w, fcf_b,
        (float*)d_out, M);
}

// Round 14
// 181.965 us; speedup vs baseline: 1.0770x; 1.0770x over previous
//
#include <hip/hip_runtime.h>
#include <hip/hip_bf16.h>
#include <cmath>

#define TEXTD 500
#define GNN_DIM 128
#define DEGP(v) ((v) << 5)   // one counter per 128B line

typedef __attribute__((ext_vector_type(8))) short bf16x8;
typedef __attribute__((ext_vector_type(4))) float f32x4;

__device__ __forceinline__ float bf2f(unsigned short u) {
    union { unsigned int i; float f; } cv;
    cv.i = ((unsigned int)u) << 16;
    return cv.f;
}
__device__ __forceinline__ unsigned short f2b(float x) {
    __hip_bfloat16 b = __float2bfloat16(x);
    return *reinterpret_cast<unsigned short*>(&b);
}
__device__ __forceinline__ float u2f(unsigned int u) {
    union { unsigned int i; float f; } cv; cv.i = u; return cv.f;
}
__device__ __forceinline__ bf16x8 cvt8(const float* p) {
    float4 u = *(const float4*)p;
    float4 v = *(const float4*)(p + 4);
    bf16x8 f;
    f[0] = (short)f2b(u.x); f[1] = (short)f2b(u.y);
    f[2] = (short)f2b(u.z); f[3] = (short)f2b(u.w);
    f[4] = (short)f2b(v.x); f[5] = (short)f2b(v.y);
    f[6] = (short)f2b(v.z); f[7] = (short)f2b(v.w);
    return f;
}

// ---------------- setup: zero padded deg counters + ALL weight conversions ----------------
// layout offsets (bf16 elems): w1cat 0..73727, w1g ..90111, w2t ..92159,
// fc2t ..100351, fc3t ..101375, fc4t ..101887
__global__ __launch_bounds__(256) void setup_kernel(
    int* __restrict__ deg, int N, int NB,
    const float* __restrict__ fc1_w, const float* __restrict__ sc_w,
    const float* __restrict__ W1, const float* __restrict__ W2,
    const float* __restrict__ fc2_w, const float* __restrict__ fc3_w,
    const float* __restrict__ fc4_w,
    unsigned short* __restrict__ w1cat, unsigned short* __restrict__ w1g,
    unsigned short* __restrict__ w2t, unsigned short* __restrict__ fc2t,
    unsigned short* __restrict__ fc3t, unsigned short* __restrict__ fc4t)
{
    if ((int)blockIdx.x < NB) {
        int v = blockIdx.x * 256 + threadIdx.x;
        if (v < N) deg[DEGP(v)] = 0;
        return;
    }
    int idx = (blockIdx.x - NB) * 256 + threadIdx.x;
    if (idx < 73728) {                       // w1cat [144][512]
        int n = idx >> 9, k = idx & 511;
        float v = 0.f;
        if (k < TEXTD) v = (n < 128) ? fc1_w[k * 128 + n] : sc_w[k * 16 + (n - 128)];
        w1cat[idx] = f2b(v);
    } else if (idx < 90112) {                // w1g [128][128]
        int j = idx - 73728;
        int n = j >> 7, k = j & 127;
        w1g[j] = f2b(W1[k * 128 + n]);
    } else if (idx < 92160) {                // w2t [16][128]
        int j = idx - 90112;
        int n = j >> 7, k = j & 127;
        w2t[j] = f2b(W2[k * 16 + n]);
    } else if (idx < 100352) {               // fc2t [64][128]
        int j = idx - 92160;
        int n = j >> 7, k = j & 127;
        fc2t[j] = f2b(fc2_w[k * 64 + n]);
    } else if (idx < 101376) {               // fc3t [16][64]
        int j = idx - 100352;
        int n = j >> 6, k = j & 63;
        fc3t[j] = f2b(fc3_w[k * 16 + n]);
    } else if (idx < 101888) {               // fc4t [16][32] (K zero-padded)
        int j = idx - 101376;
        int n = j >> 5, k = j & 31;
        fc4t[j] = f2b((k < 16) ? fc4_w[k * 16 + n] : 0.f);
    }
}

// ---------------- fully-MFMA text branch: 1 wave / 16 rows ----------------
__global__ __launch_bounds__(64) void text_mfma_kernel(
    const float* __restrict__ text, const short* __restrict__ w1cat,
    const float* __restrict__ fc1_b, const float* __restrict__ sc_b,
    const short* __restrict__ fc2t, const float* __restrict__ fc2_b,
    const short* __restrict__ fc3t, const float* __restrict__ fc3_b,
    const short* __restrict__ fc4t, const float* __restrict__ fc4_b,
    float* __restrict__ text_out, int M)
{
    __shared__ unsigned short t1b[16 * 136];   // bf16, padded stride (2-way banks)
    __shared__ unsigned short t2b[16 * 72];
    __shared__ unsigned short t3b[16 * 40];    // cols 16..31 zeroed (K-pad for fc4)
    __shared__ float tscs[16 * 16];

    const int lane = threadIdx.x;
    const int q = lane >> 4, col = lane & 15;
    const int mb = blockIdx.x * 16;
    const int arow = min(mb + col, M - 1);
    const float* ap = text + (size_t)arow * TEXTD + q * 8;

    // --- phase 1: fc1 (relu+b) + shortcut, A in registers ---
    bf16x8 afrag[16];
    #pragma unroll
    for (int ks = 0; ks < 15; ks++) afrag[ks] = cvt8(ap + ks * 32);
    {   // K 480..511, zero-pad past 500
        bf16x8 f;
        int k0 = 480 + q * 8;
        #pragma unroll
        for (int e = 0; e < 8; e++) {
            int k = k0 + e;
            f[e] = (short)((k < TEXTD) ? f2b(text[(size_t)arow * TEXTD + k]) : 0);
        }
        afrag[15] = f;
    }

    for (int nb = 0; nb < 9; nb++) {
        const short* bp = w1cat + (size_t)(nb * 16 + col) * 512 + q * 8;
        f32x4 acc = {0.f, 0.f, 0.f, 0.f};
        #pragma unroll
        for (int ks = 0; ks < 16; ks++)
            acc = __builtin_amdgcn_mfma_f32_16x16x32_bf16(afrag[ks], *(const bf16x8*)(bp + ks * 32), acc, 0, 0, 0);
        #pragma unroll
        for (int i = 0; i < 4; i++) {
            int row = q * 4 + i;
            if (nb < 8) t1b[row * 136 + nb * 16 + col] = f2b(fmaxf(acc[i] + fc1_b[nb * 16 + col], 0.f));
            else        tscs[row * 16 + col] = acc[i] + sc_b[col];
        }
    }
    __syncthreads();

    // --- phase 2: fc2 (16x64, K=128) ---
    const unsigned short* a2p = t1b + col * 136 + q * 8;
    #pragma unroll
    for (int nt = 0; nt < 4; nt++) {
        const short* bp = fc2t + (nt * 16 + col) * 128 + q * 8;
        f32x4 acc = {0.f, 0.f, 0.f, 0.f};
        #pragma unroll
        for (int ks = 0; ks < 4; ks++)
            acc = __builtin_amdgcn_mfma_f32_16x16x32_bf16(
                *(const bf16x8*)(a2p + ks * 32), *(const bf16x8*)(bp + ks * 32), acc, 0, 0, 0);
        #pragma unroll
        for (int i = 0; i < 4; i++) {
            int row = q * 4 + i;
            t2b[row * 72 + nt * 16 + col] = f2b(fmaxf(acc[i] + fc2_b[nt * 16 + col], 0.f));
        }
    }
    __syncthreads();

    // --- phase 3: fc3 (16x16, K=64) ---
    {
        const unsigned short* a3p = t2b + col * 72 + q * 8;
        const short* bp = fc3t + col * 64 + q * 8;
        f32x4 acc = {0.f, 0.f, 0.f, 0.f};
        #pragma unroll
        for (int ks = 0; ks < 2; ks++)
            acc = __builtin_amdgcn_mfma_f32_16x16x32_bf16(
                *(const bf16x8*)(a3p + ks * 32), *(const bf16x8*)(bp + ks * 32), acc, 0, 0, 0);
        #pragma unroll
        for (int i = 0; i < 4; i++) {
            int row = q * 4 + i;
            t3b[row * 40 + col] = f2b(fmaxf(acc[i] + fc3_b[col], 0.f));
            t3b[row * 40 + 16 + col] = 0;   // K-pad
        }
    }
    __syncthreads();

    // --- phase 4: fc4 (16x16, K=32 padded) + shortcut + store ---
    {
        const unsigned short* a4p = t3b + col * 40 + q * 8;
        const short* bp = fc4t + col * 32 + q * 8;
        f32x4 acc = {0.f, 0.f, 0.f, 0.f};
        acc = __builtin_amdgcn_mfma_f32_16x16x32_bf16(
            *(const bf16x8*)a4p, *(const bf16x8*)bp, acc, 0, 0, 0);
        #pragma unroll
        for (int i = 0; i < 4; i++) {
            int row = q * 4 + i;
            int rg = mb + row;
            if (rg < M) text_out[(size_t)rg * 16 + col] = acc[i] + fc4_b[col] + tscs[row * 16 + col];
        }
    }
}

// ---------------- GEMM2: x[fp32, Nx128] @ W1 -> h1 bf16; fused a_s1/a_d1 epilogue ----------------
__global__ __launch_bounds__(256) void gemm_h1_kernel(
    const float* __restrict__ x, const short* __restrict__ B,
    const float* __restrict__ as1w, const float* __restrict__ ad1w,
    unsigned short* __restrict__ h1, float* __restrict__ a_s, float* __restrict__ a_d, int N)
{
    const int tid = threadIdx.x;
    const int wave = tid >> 6, lane = tid & 63;
    const int q = lane >> 4, col = lane & 15;
    const int mb = blockIdx.x * 64 + wave * 16;
    const int arow = min(mb + col, N - 1);
    const float* ap = x + (size_t)arow * 128 + q * 8;

    bf16x8 afrag[4];
    #pragma unroll
    for (int ks = 0; ks < 4; ks++) afrag[ks] = cvt8(ap + ks * 32);

    float ps0[4] = {0,0,0,0}, ps1[4] = {0,0,0,0};
    float pd0[4] = {0,0,0,0}, pd1[4] = {0,0,0,0};

    #pragma unroll
    for (int nb = 0; nb < 8; nb++) {
        const short* bp = B + (size_t)(nb * 16 + col) * 128 + q * 8;
        f32x4 acc = {0.f, 0.f, 0.f, 0.f};
        #pragma unroll
        for (int ks = 0; ks < 4; ks++)
            acc = __builtin_amdgcn_mfma_f32_16x16x32_bf16(afrag[ks], *(const bf16x8*)(bp + ks * 32), acc, 0, 0, 0);
        const int j = nb * 16 + col;
        const float asj = as1w[j], adj = ad1w[j];
        #pragma unroll
        for (int i = 0; i < 4; i++) {
            int row = mb + q * 4 + i;
            if (row < N) h1[(size_t)row * 128 + j] = f2b(acc[i]);
            if (nb < 4) { ps0[i] = fmaf(acc[i], asj, ps0[i]); pd0[i] = fmaf(acc[i], adj, pd0[i]); }
            else        { ps1[i] = fmaf(acc[i], asj, ps1[i]); pd1[i] = fmaf(acc[i], adj, pd1[i]); }
        }
    }
    #pragma unroll
    for (int i = 0; i < 4; i++) {
        float v0 = ps0[i], v1 = ps1[i], w0 = pd0[i], w1 = pd1[i];
        #pragma unroll
        for (int off = 1; off < 16; off <<= 1) {
            v0 += __shfl_xor(v0, off, 16);
            v1 += __shfl_xor(v1, off, 16);
            w0 += __shfl_xor(w0, off, 16);
            w1 += __shfl_xor(w1, off, 16);
        }
        int row = mb + q * 4 + i;
        if (col == 0 && row < N) {
            a_s[2 * row] = v0; a_s[2 * row + 1] = v1;
            a_d[2 * row] = w0; a_d[2 * row + 1] = w1;
        }
    }
}

// ---------------- CSR build ----------------
__global__ __launch_bounds__(256) void deg_hist_kernel(
    const int* __restrict__ edst, int* __restrict__ deg, int* __restrict__ rank, int E)
{
    const int base = blockIdx.x * 1024 + threadIdx.x;
    int e0 = base;
    int e1 = base + 256;
    int e2 = base + 512;
    int e3 = base + 768;
    int d0 = (e0 < E) ? edst[e0] : -1;
    int d1 = (e1 < E) ? edst[e1] : -1;
    int d2 = (e2 < E) ? edst[e2] : -1;
    int d3 = (e3 < E) ? edst[e3] : -1;
    int r0 = (d0 >= 0) ? atomicAdd(&deg[DEGP(d0)], 1) : 0;
    int r1 = (d1 >= 0) ? atomicAdd(&deg[DEGP(d1)], 1) : 0;
    int r2 = (d2 >= 0) ? atomicAdd(&deg[DEGP(d2)], 1) : 0;
    int r3 = (d3 >= 0) ? atomicAdd(&deg[DEGP(d3)], 1) : 0;
    if (d0 >= 0) rank[e0] = r0;
    if (d1 >= 0) rank[e1] = r1;
    if (d2 >= 0) rank[e2] = r2;
    if (d3 >= 0) rank[e3] = r3;
}

// phase 1: per-256-tile sums of (deg[i]+1)
__global__ __launch_bounds__(256) void part_kernel(
    const int* __restrict__ deg, int* __restrict__ bsum, int N)
{
    const int tid = threadIdx.x;
    int i = blockIdx.x * 256 + tid;
    int d = (i < N) ? deg[DEGP(i)] + 1 : 0;
    #pragma unroll
    for (int off = 32; off > 0; off >>= 1) d += __shfl_down(d, off, 64);
    __shared__ int wsum[4];
    if ((tid & 63) == 0) wsum[tid >> 6] = d;
    __syncthreads();
    if (tid == 0) bsum[blockIdx.x] = wsum[0] + wsum[1] + wsum[2] + wsum[3];
}

// phase 2 (fused): each block scans bsum in LDS, then in-block element scan -> rowptr
__global__ __launch_bounds__(256) void rowptr_kernel(
    const int* __restrict__ deg, const int* __restrict__ bsum,
    int* __restrict__ rowptr, int N, int NB)
{
    __shared__ int bsc[256];
    __shared__ int sc[256];
    const int tid = threadIdx.x;

    int bv = (tid < NB) ? bsum[tid] : 0;
    bsc[tid] = bv;
    for (int off = 1; off < 256; off <<= 1) {
        __syncthreads();
        int t = (tid >= off) ? bsc[tid - off] : 0;
        __syncthreads();
        bsc[tid] += t;
    }
    __syncthreads();
    const int base = (blockIdx.x == 0) ? 0 : bsc[blockIdx.x - 1];

    const int i = blockIdx.x * 256 + tid;
    int d = (i < N) ? deg[DEGP(i)] + 1 : 0;
    sc[tid] = d;
    for (int off = 1; off < 256; off <<= 1) {
        __syncthreads();
        int t = (tid >= off) ? sc[tid - off] : 0;
        __syncthreads();
        sc[tid] += t;
    }
    __syncthreads();
    int incl = sc[tid];
    if (i < N) rowptr[i] = base + incl - d;
    if (i == N - 1) rowptr[N] = base + incl;
}

__device__ __forceinline__ float edge_w(float e) {
    return __expf(e > 0.f ? e : 0.2f * e);
}

// fill CSR slots: single 8B store per edge {src, bf16 w0 | w1<<16}; no atomics
__global__ __launch_bounds__(256) void fillw_kernel(
    const int* __restrict__ esrc, const int* __restrict__ edst,
    const int* __restrict__ rank, const int* __restrict__ rowptr,
    uint2* __restrict__ eslot,
    const float* __restrict__ a_s, const float* __restrict__ a_d, int E, int N)
{
    int e = blockIdx.x * 256 + threadIdx.x;
    if (e < E) {
        int src = esrc[e], dst = edst[e];
        int pos = rowptr[dst] + 1 + rank[e];
        float2 as = *(const float2*)(a_s + 2 * src);
        float2 ad = *(const float2*)(a_d + 2 * dst);
        unsigned int w0 = f2b(edge_w(as.x + ad.x));
        unsigned int w1 = f2b(edge_w(as.y + ad.y));
        uint2 o; o.x = (unsigned int)src; o.y = (w1 << 16) | w0;
        eslot[pos] = o;
    } else if (e < E + N) {
        int v = e - E;
        float2 as = *(const float2*)(a_s + 2 * v);
        float2 ad = *(const float2*)(a_d + 2 * v);
        unsigned int w0 = f2b(edge_w(as.x + ad.x));
        unsigned int w1 = f2b(edge_w(as.y + ad.y));
        uint2 o; o.x = (unsigned int)v; o.y = (w1 << 16) | w0;
        eslot[rowptr[v]] = o;
    }
}

// ---------------- layer-1 gather: 1 WAVE/node (4 nodes/block), 2 slots x 32 lanes(x4 dims) ----------------
template<int B>
__device__ __forceinline__ void gat1_batch(
    int i0, int end, int endm1, int wsh,
    const uint2* __restrict__ eslot, const uint2* __restrict__ h1u, unsigned int dp,
    float& a0, float& a1, float& a2, float& a3, float& den)
{
    int ics[B];
    uint2 sl[B];
    float wv[B];
    uint2 hv[B];
    #pragma unroll
    for (int k = 0; k < B; k++) ics[k] = min(i0 + 2 * k, endm1);
    #pragma unroll
    for (int k = 0; k < B; k++) sl[k] = eslot[ics[k]];
    #pragma unroll
    for (int k = 0; k < B; k++) {
        float w = u2f((sl[k].y << wsh) & 0xffff0000u);
        wv[k] = (i0 + 2 * k < end) ? w : 0.f;
    }
    #pragma unroll
    for (int k = 0; k < B; k++) hv[k] = h1u[(sl[k].x << 5) | dp];
    #pragma unroll
    for (int k = 0; k < B; k++) {
        float w = wv[k];
        den += w;
        a0 = fmaf(w, u2f(hv[k].x << 16),          a0);
        a1 = fmaf(w, u2f(hv[k].x & 0xffff0000u),  a1);
        a2 = fmaf(w, u2f(hv[k].y << 16),          a2);
        a3 = fmaf(w, u2f(hv[k].y & 0xffff0000u),  a3);
    }
}

__global__ __launch_bounds__(256) void gat1_gather_kernel(
    const int* __restrict__ rowptr, const uint2* __restrict__ eslot,
    const uint2* __restrict__ h1u,
    const float* __restrict__ b1, uint2* __restrict__ g1b, int N)
{
    const int v = blockIdx.x * 4 + (threadIdx.x >> 6);
    if (v >= N) return;
    const int lane = threadIdx.x & 63;
    const int slot = lane >> 5;
    const unsigned int dp = lane & 31;
    const int head = dp >> 4;
    const int wsh = head ? 0 : 16;
    const int beg = rowptr[v], end = rowptr[v + 1];
    const int deg = end - beg;
    const int endm1 = end - 1;
    const int i0 = beg + slot;

    float a0 = 0.f, a1 = 0.f, a2 = 0.f, a3 = 0.f, den = 0.f;

    if (deg <= 8) {
        gat1_batch<4>(i0, end, endm1, wsh, eslot, h1u, dp, a0, a1, a2, a3, den);
    } else {
        gat1_batch<8>(i0, end, endm1, wsh, eslot, h1u, dp, a0, a1, a2, a3, den);
        for (int base = i0 + 16; base < end; base += 8)
            gat1_batch<4>(base, end, endm1, wsh, eslot, h1u, dp, a0, a1, a2, a3, den);
    }

    a0 += __shfl_xor(a0, 32, 64);
    a1 += __shfl_xor(a1, 32, 64);
    a2 += __shfl_xor(a2, 32, 64);
    a3 += __shfl_xor(a3, 32, 64);
    den += __shfl_xor(den, 32, 64);

    if (lane < 32) {
        float inv = 1.f / (den + 1e-16f);
        float4 bv = *(const float4*)(b1 + 4 * dp);
        float o0 = fmaxf(fmaf(a0, inv, bv.x), 0.f);
        float o1 = fmaxf(fmaf(a1, inv, bv.y), 0.f);
        float o2 = fmaxf(fmaf(a2, inv, bv.z), 0.f);
        float o3 = fmaxf(fmaf(a3, inv, bv.w), 0.f);
        uint2 o;
        o.x = ((unsigned int)f2b(o1) << 16) | f2b(o0);
        o.y = ((unsigned int)f2b(o3) << 16) | f2b(o2);
        g1b[((unsigned int)v << 5) | dp] = o;
    }
}

// ---------------- gat2 projection (MFMA): h2 = g1b @ W2; fused a_s2/a_d2 ----------------
__global__ __launch_bounds__(256) void gat2_proj_kernel(
    const unsigned short* __restrict__ g1b, const short* __restrict__ w2t,
    const float* __restrict__ as2w, const float* __restrict__ ad2w,
    float* __restrict__ h2, float* __restrict__ a_s2, float* __restrict__ a_d2, int N)
{
    const int tid = threadIdx.x;
    const int wave = tid >> 6, lane = tid & 63;
    const int q = lane >> 4, col = lane & 15;
    const int mb = blockIdx.x * 64 + wave * 16;
    const int arow = min(mb + col, N - 1);
    const short* ap = (const short*)g1b + (size_t)arow * 128 + q * 8;
    const short* bp = w2t + (size_t)col * 128 + q * 8;

    f32x4 acc = {0.f, 0.f, 0.f, 0.f};
    #pragma unroll
    for (int ks = 0; ks < 4; ks++)
        acc = __builtin_amdgcn_mfma_f32_16x16x32_bf16(
            *(const bf16x8*)(ap + ks * 32), *(const bf16x8*)(bp + ks * 32), acc, 0, 0, 0);

    const float asj = as2w[col], adj = ad2w[col];
    #pragma unroll
    for (int i = 0; i < 4; i++) {
        int row = mb + q * 4 + i;
        float ps = acc[i] * asj, pd = acc[i] * adj;
        #pragma unroll
        for (int off = 1; off < 16; off <<= 1) {
            ps += __shfl_xor(ps, off, 16);
            pd += __shfl_xor(pd, off, 16);
        }
        if (row < N) {
            h2[(size_t)row * 16 + col] = acc[i];
            if (col == 0) { a_s2[row] = ps; a_d2[row] = pd; }
        }
    }
}

// ---------------- fused layer-2 gather + head (4 masked nodes/block) ----------------
__global__ __launch_bounds__(256) void gat2_final_kernel(
    const int* __restrict__ rowptr, const uint2* __restrict__ eslot,
    const float* __restrict__ h2,
    const float* __restrict__ a_s2, const float* __restrict__ a_d2,
    const float* __restrict__ b2, const int* __restrict__ mask,
    const float* __restrict__ text_out,
    const float* __restrict__ fcf_w, const float* __restrict__ fcf_b,
    float* __restrict__ out, int M)
{
    const int tid = threadIdx.x;
    const int m = blockIdx.x * 4 + (tid >> 6);
    if (m >= M) return;
    const int lane = tid & 63, slot = lane >> 4, c = lane & 15;
    const int v = mask[m];
    const float adv = a_d2[v];
    const int beg = rowptr[v], end = rowptr[v + 1];
    const int i0 = beg + slot;

    float acc = 0.f, den = 0.f;
    unsigned int idxs[8];
    float msk[8], as_[8], hval[8];
    #pragma unroll
    for (int k = 0; k < 8; k++) {
        int i = i0 + 4 * k;
        int ic = min(i, end - 1);
        idxs[k] = eslot[ic].x;
        msk[k] = (i < end) ? 1.f : 0.f;
    }
    #pragma unroll
    for (int k = 0; k < 8; k++) as_[k] = a_s2[idxs[k]];
    #pragma unroll
    for (int k = 0; k < 8; k++) hval[k] = h2[(idxs[k] << 4) | (unsigned)c];
    #pragma unroll
    for (int k = 0; k < 8; k++) {
        float e = as_[k] + adv;
        float w = msk[k] * __expf(e > 0.f ? e : 0.2f * e);
        den += w;
        acc = fmaf(w, hval[k], acc);
    }
    for (int i = i0 + 32; i < end; i += 4) {
        unsigned int src = eslot[i].x;
        float e = a_s2[src] + adv;
        float w = __expf(e > 0.f ? e : 0.2f * e);
        den += w;
        acc = fmaf(w, h2[(src << 4) | (unsigned)c], acc);
    }

    acc += __shfl_xor(acc, 16, 64);
    acc += __shfl_xor(acc, 32, 64);
    den += __shfl_xor(den, 16, 64);
    den += __shfl_xor(den, 32, 64);

    if (slot == 0) {
        float gval = acc / (den + 1e-16f) + b2[c];
        float tval = text_out[(size_t)m * 16 + c];

        float logit = fcf_b[c];
        #pragma unroll
        for (int k = 0; k < 16; k++) {
            logit = fmaf(__shfl(tval, k, 16), fcf_w[k * 16 + c], logit);
            logit = fmaf(__shfl(gval, k, 16), fcf_w[(16 + k) * 16 + c], logit);
        }
        float mx = logit;
        #pragma unroll
        for (int off = 8; off > 0; off >>= 1) mx = fmaxf(mx, __shfl_xor(mx, off, 16));
        float se = expf(logit - mx);
        #pragma unroll
        for (int off = 8; off > 0; off >>= 1) se += __shfl_xor(se, off, 16);
        out[(size_t)m * 16 + c] = logit - mx - logf(se);
    }
}

extern "C" void kernel_launch(void* const* d_in, const int* in_sizes, int n_in,
                              void* d_out, int out_size, void* d_ws, size_t ws_size,
                              hipStream_t stream)
{
    const float* text  = (const float*)d_in[0];
    const float* x     = (const float*)d_in[1];
    const int*   ei    = (const int*)  d_in[2];
    const int*   mask  = (const int*)  d_in[3];
    const float* fc1_w = (const float*)d_in[4];  const float* fc1_b = (const float*)d_in[5];
    const float* fc2_w = (const float*)d_in[6];  const float* fc2_b = (const float*)d_in[7];
    const float* fc3_w = (const float*)d_in[8];  const float* fc3_b = (const float*)d_in[9];
    const float* fc4_w = (const float*)d_in[10]; const float* fc4_b = (const float*)d_in[11];
    const float* sc_w  = (const float*)d_in[12]; const float* sc_b  = (const float*)d_in[13];
    const float* W1    = (const float*)d_in[14];
    const float* as1w  = (const float*)d_in[15]; const float* ad1w  = (const float*)d_in[16];
    const float* b1    = (const float*)d_in[17];
    const float* W2    = (const float*)d_in[18];
    const float* as2w  = (const float*)d_in[19]; const float* ad2w  = (const float*)d_in[20];
    const float* b2    = (const float*)d_in[21];
    const float* fcf_w = (const float*)d_in[22]; const float* fcf_b = (const float*)d_in[23];

    const int M  = in_sizes[3];
    const int N  = in_sizes[1] / GNN_DIM;
    const int E  = in_sizes[2] / 2;
    const int EP = E + N;
    const int* esrc = ei;
    const int* edst = ei + E;

    const int Np = ((N + 63) / 64) * 64;
    const int NB = (N + 255) / 256;        // <= 256

    float* ws = (float*)d_ws;
    size_t off = 0;
    auto alloc = [&](size_t n) { float* p = ws + off; off += (n + 63) & ~size_t(63); return p; };

    unsigned short* h1    = (unsigned short*)alloc((size_t)Np * 64);   // bf16 [Np x 128]
    unsigned int*   g1b   = (unsigned int*)  alloc((size_t)N * 64);    // bf16 [N x 128] packed
    unsigned short* w1cat = (unsigned short*)alloc(144 * 256);         // bf16 [144 x 512]
    unsigned short* w1g   = (unsigned short*)alloc(128 * 64);          // bf16 [128 x 128]
    unsigned short* w2t   = (unsigned short*)alloc(16 * 64);           // bf16 [16 x 128]
    unsigned short* fc2t  = (unsigned short*)alloc(64 * 64);           // bf16 [64 x 128]
    unsigned short* fc3t  = (unsigned short*)alloc(16 * 32);           // bf16 [16 x 64]
    unsigned short* fc4t  = (unsigned short*)alloc(16 * 16);           // bf16 [16 x 32]
    float* a_s1     = alloc((size_t)2 * N);
    float* a_d1     = alloc((size_t)2 * N);
    float* h2       = alloc((size_t)N * 16);
    float* a_s2     = alloc(N);
    float* a_d2     = alloc(N);
    float* text_out = alloc((size_t)M * 16);
    uint2* eslot    = (uint2*)alloc((size_t)2 * EP);   // {src, bf16w0|bf16w1<<16}
    int* deg        = (int*)alloc((size_t)N * 32);     // padded: 1 counter / 128B
    int* rank       = (int*)alloc(E);
    int* rowptr     = (int*)alloc(N + 1);
    int* bsum       = (int*)alloc(256);

    const int convBlocks = (101888 + 255) / 256;

    // --- setup: zero counters + all weights to bf16 (one kernel) ---
    setup_kernel<<<NB + convBlocks, 256, 0, stream>>>(
        deg, N, NB, fc1_w, sc_w, W1, W2, fc2_w, fc3_w, fc4_w,
        w1cat, w1g, w2t, fc2t, fc3t, fc4t);

    // --- CSR: histogram(+rank) -> part sums -> rowptr (inline bsum scan) ---
    deg_hist_kernel<<<(E + 1023) / 1024, 256, 0, stream>>>(edst, deg, rank, E);
    part_kernel<<<NB, 256, 0, stream>>>(deg, bsum, N);
    rowptr_kernel<<<NB, 256, 0, stream>>>(deg, bsum, rowptr, N, NB);

    // --- GAT1 projection (produces a_s1/a_d1 for weight fill) ---
    gemm_h1_kernel<<<Np / 64, 256, 0, stream>>>(
        x, (const short*)w1g, as1w, ad1w, h1, a_s1, a_d1, N);

    // --- CSR fill: single 8B slot per edge, no atomics ---
    fillw_kernel<<<(E + N + 255) / 256, 256, 0, stream>>>(
        esrc, edst, rank, rowptr, eslot, a_s1, a_d1, E, N);

    // --- text branch: fully-MFMA fused, 1 wave / 16 rows ---
    text_mfma_kernel<<<(M + 15) / 16, 64, 0, stream>>>(
        text, (const short*)w1cat, fc1_b, sc_b,
        (const short*)fc2t, fc2_b, (const short*)fc3t, fc3_b,
        (const short*)fc4t, fc4_b, text_out, M);

    // --- GNN aggregation / second layer ---
    gat1_gather_kernel<<<(N + 3) / 4, 256, 0, stream>>>(
        rowptr, eslot, (const uint2*)h1, b1, (uint2*)g1b, N);

    gat2_proj_kernel<<<Np / 64, 256, 0, stream>>>(
        (const unsigned short*)g1b, (const short*)w2t, as2w, ad2w, h2, a_s2, a_d2, N);

    // --- fused layer-2 gather + head ---
    gat2_final_kernel<<<(M + 3) / 4, 256, 0, stream>>>(
        rowptr, eslot, h2, a_s2, a_d2, b2, mask, text_out, fcf_w, fcf_b,
        (float*)d_out, M);
}

// Round 15
// 164.693 us; speedup vs baseline: 1.1899x; 1.1049x over previous
//
#include <hip/hip_runtime.h>
#include <hip/hip_bf16.h>
#include <cmath>

#define TEXTD 500
#define GNN_DIM 128
#define DEGP(v) ((v) << 5)   // one counter per 128B line

typedef __attribute__((ext_vector_type(8))) short bf16x8;
typedef __attribute__((ext_vector_type(4))) float f32x4;

__device__ __forceinline__ float bf2f(unsigned short u) {
    union { unsigned int i; float f; } cv;
    cv.i = ((unsigned int)u) << 16;
    return cv.f;
}
__device__ __forceinline__ unsigned short f2b(float x) {
    __hip_bfloat16 b = __float2bfloat16(x);
    return *reinterpret_cast<unsigned short*>(&b);
}
__device__ __forceinline__ float u2f(unsigned int u) {
    union { unsigned int i; float f; } cv; cv.i = u; return cv.f;
}
__device__ __forceinline__ bf16x8 cvt8(const float* p) {
    float4 u = *(const float4*)p;
    float4 v = *(const float4*)(p + 4);
    bf16x8 f;
    f[0] = (short)f2b(u.x); f[1] = (short)f2b(u.y);
    f[2] = (short)f2b(u.z); f[3] = (short)f2b(u.w);
    f[4] = (short)f2b(v.x); f[5] = (short)f2b(v.y);
    f[6] = (short)f2b(v.z); f[7] = (short)f2b(v.w);
    return f;
}

// ---------------- setup: zero padded deg counters + ALL weight conversions ----------------
__global__ __launch_bounds__(256) void setup_kernel(
    int* __restrict__ deg, int N, int NB,
    const float* __restrict__ fc1_w, const float* __restrict__ sc_w,
    const float* __restrict__ W1, const float* __restrict__ W2,
    const float* __restrict__ fc2_w, const float* __restrict__ fc3_w,
    const float* __restrict__ fc4_w,
    unsigned short* __restrict__ w1cat, unsigned short* __restrict__ w1g,
    unsigned short* __restrict__ w2t, unsigned short* __restrict__ fc2t,
    unsigned short* __restrict__ fc3t, unsigned short* __restrict__ fc4t)
{
    if ((int)blockIdx.x < NB) {
        int v = blockIdx.x * 256 + threadIdx.x;
        if (v < N) deg[DEGP(v)] = 0;
        return;
    }
    int idx = (blockIdx.x - NB) * 256 + threadIdx.x;
    if (idx < 73728) {                       // w1cat [144][512]
        int n = idx >> 9, k = idx & 511;
        float v = 0.f;
        if (k < TEXTD) v = (n < 128) ? fc1_w[k * 128 + n] : sc_w[k * 16 + (n - 128)];
        w1cat[idx] = f2b(v);
    } else if (idx < 90112) {                // w1g [128][128]
        int j = idx - 73728;
        int n = j >> 7, k = j & 127;
        w1g[j] = f2b(W1[k * 128 + n]);
    } else if (idx < 92160) {                // w2t [16][128]
        int j = idx - 90112;
        int n = j >> 7, k = j & 127;
        w2t[j] = f2b(W2[k * 16 + n]);
    } else if (idx < 100352) {               // fc2t [64][128]
        int j = idx - 92160;
        int n = j >> 7, k = j & 127;
        fc2t[j] = f2b(fc2_w[k * 64 + n]);
    } else if (idx < 101376) {               // fc3t [16][64]
        int j = idx - 100352;
        int n = j >> 6, k = j & 63;
        fc3t[j] = f2b(fc3_w[k * 16 + n]);
    } else if (idx < 101888) {               // fc4t [16][32] (K zero-padded)
        int j = idx - 101376;
        int n = j >> 5, k = j & 31;
        fc4t[j] = f2b((k < 16) ? fc4_w[k * 16 + n] : 0.f);
    }
}

// ---------------- fully-MFMA text branch: K-split-4, 4 waves / 16-row tile ----------------
__global__ __launch_bounds__(256) void text_mfma_kernel(
    const float* __restrict__ text, const short* __restrict__ w1cat,
    const float* __restrict__ fc1_b, const float* __restrict__ sc_b,
    const short* __restrict__ fc2t, const float* __restrict__ fc2_b,
    const short* __restrict__ fc3t, const float* __restrict__ fc3_b,
    const short* __restrict__ fc4t, const float* __restrict__ fc4_b,
    float* __restrict__ text_out, int M)
{
    __shared__ float part[4 * 9 * 256];        // [w][nb][i][lane], 36 KB
    __shared__ unsigned short t1b[16 * 136];   // bf16, padded stride
    __shared__ unsigned short t2b[16 * 72];
    __shared__ unsigned short t3b[16 * 40];    // cols 16..31 zeroed (K-pad for fc4)
    __shared__ float tscs[16 * 16];

    const int tid = threadIdx.x;
    const int w = tid >> 6, lane = tid & 63;
    const int q = lane >> 4, col = lane & 15;
    const int mb = blockIdx.x * 16;
    const int arow = min(mb + col, M - 1);
    const int kofs = w * 128;

    // --- phase 1: fc1+shortcut partials over K slice [128w, 128w+128) ---
    bf16x8 afrag[4];
    #pragma unroll
    for (int ks = 0; ks < 4; ks++) {
        int k0 = kofs + ks * 32 + q * 8;
        if (k0 + 7 < TEXTD) {
            afrag[ks] = cvt8(text + (size_t)arow * TEXTD + k0);
        } else {
            bf16x8 f;
            #pragma unroll
            for (int e = 0; e < 8; e++) {
                int k = k0 + e;
                f[e] = (short)((k < TEXTD) ? f2b(text[(size_t)arow * TEXTD + k]) : 0);
            }
            afrag[ks] = f;
        }
    }

    for (int nb = 0; nb < 9; nb++) {
        const short* bp = w1cat + (size_t)(nb * 16 + col) * 512 + kofs + q * 8;
        f32x4 acc = {0.f, 0.f, 0.f, 0.f};
        #pragma unroll
        for (int ks = 0; ks < 4; ks++)
            acc = __builtin_amdgcn_mfma_f32_16x16x32_bf16(afrag[ks], *(const bf16x8*)(bp + ks * 32), acc, 0, 0, 0);
        #pragma unroll
        for (int i = 0; i < 4; i++)
            part[w * 2304 + nb * 256 + i * 64 + lane] = acc[i];
    }
    __syncthreads();

    // --- reduce partials: waves 0-2 take 2 nb each, wave 3 takes 3 ---
    {
        int nb0 = w * 2;
        int cnt = (w == 3) ? 3 : 2;
        for (int t = 0; t < cnt; t++) {
            int nb = nb0 + t;
            #pragma unroll
            for (int i = 0; i < 4; i++) {
                float a = part[nb * 256 + i * 64 + lane]
                        + part[2304 + nb * 256 + i * 64 + lane]
                        + part[4608 + nb * 256 + i * 64 + lane]
                        + part[6912 + nb * 256 + i * 64 + lane];
                int row = q * 4 + i;
                if (nb < 8) t1b[row * 136 + nb * 16 + col] = f2b(fmaxf(a + fc1_b[nb * 16 + col], 0.f));
                else        tscs[row * 16 + col] = a + sc_b[col];
            }
        }
    }
    __syncthreads();

    // --- phase 2: fc2 (16x64, K=128), wave w does tile nt=w ---
    {
        const unsigned short* a2p = t1b + col * 136 + q * 8;
        const short* bp = fc2t + (w * 16 + col) * 128 + q * 8;
        f32x4 acc = {0.f, 0.f, 0.f, 0.f};
        #pragma unroll
        for (int ks = 0; ks < 4; ks++)
            acc = __builtin_amdgcn_mfma_f32_16x16x32_bf16(
                *(const bf16x8*)(a2p + ks * 32), *(const bf16x8*)(bp + ks * 32), acc, 0, 0, 0);
        #pragma unroll
        for (int i = 0; i < 4; i++) {
            int row = q * 4 + i;
            t2b[row * 72 + w * 16 + col] = f2b(fmaxf(acc[i] + fc2_b[w * 16 + col], 0.f));
        }
    }
    __syncthreads();

    // --- phase 3+4: fc3, fc4 + shortcut + store (wave 0 only) ---
    if (w == 0) {
        {
            const unsigned short* a3p = t2b + col * 72 + q * 8;
            const short* bp = fc3t + col * 64 + q * 8;
            f32x4 acc = {0.f, 0.f, 0.f, 0.f};
            #pragma unroll
            for (int ks = 0; ks < 2; ks++)
                acc = __builtin_amdgcn_mfma_f32_16x16x32_bf16(
                    *(const bf16x8*)(a3p + ks * 32), *(const bf16x8*)(bp + ks * 32), acc, 0, 0, 0);
            #pragma unroll
            for (int i = 0; i < 4; i++) {
                int row = q * 4 + i;
                t3b[row * 40 + col] = f2b(fmaxf(acc[i] + fc3_b[col], 0.f));
                t3b[row * 40 + 16 + col] = 0;   // K-pad
            }
        }
        {
            const unsigned short* a4p = t3b + col * 40 + q * 8;
            const short* bp = fc4t + col * 32 + q * 8;
            f32x4 acc = {0.f, 0.f, 0.f, 0.f};
            acc = __builtin_amdgcn_mfma_f32_16x16x32_bf16(
                *(const bf16x8*)a4p, *(const bf16x8*)bp, acc, 0, 0, 0);
            #pragma unroll
            for (int i = 0; i < 4; i++) {
                int row = q * 4 + i;
                int rg = mb + row;
                if (rg < M) text_out[(size_t)rg * 16 + col] = acc[i] + fc4_b[col] + tscs[row * 16 + col];
            }
        }
    }
}

// ---------------- GEMM2: x[fp32, Nx128] @ W1 -> h1 bf16; fused a_s1/a_d1 epilogue ----------------
__global__ __launch_bounds__(256) void gemm_h1_kernel(
    const float* __restrict__ x, const short* __restrict__ B,
    const float* __restrict__ as1w, const float* __restrict__ ad1w,
    unsigned short* __restrict__ h1, float* __restrict__ a_s, float* __restrict__ a_d, int N)
{
    const int tid = threadIdx.x;
    const int wave = tid >> 6, lane = tid & 63;
    const int q = lane >> 4, col = lane & 15;
    const int mb = blockIdx.x * 64 + wave * 16;
    const int arow = min(mb + col, N - 1);
    const float* ap = x + (size_t)arow * 128 + q * 8;

    bf16x8 afrag[4];
    #pragma unroll
    for (int ks = 0; ks < 4; ks++) afrag[ks] = cvt8(ap + ks * 32);

    float ps0[4] = {0,0,0,0}, ps1[4] = {0,0,0,0};
    float pd0[4] = {0,0,0,0}, pd1[4] = {0,0,0,0};

    #pragma unroll
    for (int nb = 0; nb < 8; nb++) {
        const short* bp = B + (size_t)(nb * 16 + col) * 128 + q * 8;
        f32x4 acc = {0.f, 0.f, 0.f, 0.f};
        #pragma unroll
        for (int ks = 0; ks < 4; ks++)
            acc = __builtin_amdgcn_mfma_f32_16x16x32_bf16(afrag[ks], *(const bf16x8*)(bp + ks * 32), acc, 0, 0, 0);
        const int j = nb * 16 + col;
        const float asj = as1w[j], adj = ad1w[j];
        #pragma unroll
        for (int i = 0; i < 4; i++) {
            int row = mb + q * 4 + i;
            if (row < N) h1[(size_t)row * 128 + j] = f2b(acc[i]);
            if (nb < 4) { ps0[i] = fmaf(acc[i], asj, ps0[i]); pd0[i] = fmaf(acc[i], adj, pd0[i]); }
            else        { ps1[i] = fmaf(acc[i], asj, ps1[i]); pd1[i] = fmaf(acc[i], adj, pd1[i]); }
        }
    }
    #pragma unroll
    for (int i = 0; i < 4; i++) {
        float v0 = ps0[i], v1 = ps1[i], w0 = pd0[i], w1 = pd1[i];
        #pragma unroll
        for (int off = 1; off < 16; off <<= 1) {
            v0 += __shfl_xor(v0, off, 16);
            v1 += __shfl_xor(v1, off, 16);
            w0 += __shfl_xor(w0, off, 16);
            w1 += __shfl_xor(w1, off, 16);
        }
        int row = mb + q * 4 + i;
        if (col == 0 && row < N) {
            a_s[2 * row] = v0; a_s[2 * row + 1] = v1;
            a_d[2 * row] = w0; a_d[2 * row + 1] = w1;
        }
    }
}

// ---------------- CSR build ----------------
__global__ __launch_bounds__(256) void deg_hist_kernel(
    const int* __restrict__ edst, int* __restrict__ deg, int* __restrict__ rank, int E)
{
    const int base = blockIdx.x * 1024 + threadIdx.x;
    int e0 = base;
    int e1 = base + 256;
    int e2 = base + 512;
    int e3 = base + 768;
    int d0 = (e0 < E) ? edst[e0] : -1;
    int d1 = (e1 < E) ? edst[e1] : -1;
    int d2 = (e2 < E) ? edst[e2] : -1;
    int d3 = (e3 < E) ? edst[e3] : -1;
    int r0 = (d0 >= 0) ? atomicAdd(&deg[DEGP(d0)], 1) : 0;
    int r1 = (d1 >= 0) ? atomicAdd(&deg[DEGP(d1)], 1) : 0;
    int r2 = (d2 >= 0) ? atomicAdd(&deg[DEGP(d2)], 1) : 0;
    int r3 = (d3 >= 0) ? atomicAdd(&deg[DEGP(d3)], 1) : 0;
    if (d0 >= 0) rank[e0] = r0;
    if (d1 >= 0) rank[e1] = r1;
    if (d2 >= 0) rank[e2] = r2;
    if (d3 >= 0) rank[e3] = r3;
}

// phase 1: per-256-tile sums of (deg[i]+1)
__global__ __launch_bounds__(256) void part_kernel(
    const int* __restrict__ deg, int* __restrict__ bsum, int N)
{
    const int tid = threadIdx.x;
    int i = blockIdx.x * 256 + tid;
    int d = (i < N) ? deg[DEGP(i)] + 1 : 0;
    #pragma unroll
    for (int off = 32; off > 0; off >>= 1) d += __shfl_down(d, off, 64);
    __shared__ int wsum[4];
    if ((tid & 63) == 0) wsum[tid >> 6] = d;
    __syncthreads();
    if (tid == 0) bsum[blockIdx.x] = wsum[0] + wsum[1] + wsum[2] + wsum[3];
}

// phase 2 (fused): each block scans bsum in LDS, then in-block element scan -> rowptr
__global__ __launch_bounds__(256) void rowptr_kernel(
    const int* __restrict__ deg, const int* __restrict__ bsum,
    int* __restrict__ rowptr, int N, int NB)
{
    __shared__ int bsc[256];
    __shared__ int sc[256];
    const int tid = threadIdx.x;

    int bv = (tid < NB) ? bsum[tid] : 0;
    bsc[tid] = bv;
    for (int off = 1; off < 256; off <<= 1) {
        __syncthreads();
        int t = (tid >= off) ? bsc[tid - off] : 0;
        __syncthreads();
        bsc[tid] += t;
    }
    __syncthreads();
    const int base = (blockIdx.x == 0) ? 0 : bsc[blockIdx.x - 1];

    const int i = blockIdx.x * 256 + tid;
    int d = (i < N) ? deg[DEGP(i)] + 1 : 0;
    sc[tid] = d;
    for (int off = 1; off < 256; off <<= 1) {
        __syncthreads();
        int t = (tid >= off) ? sc[tid - off] : 0;
        __syncthreads();
        sc[tid] += t;
    }
    __syncthreads();
    int incl = sc[tid];
    if (i < N) rowptr[i] = base + incl - d;
    if (i == N - 1) rowptr[N] = base + incl;
}

__device__ __forceinline__ float edge_w(float e) {
    return __expf(e > 0.f ? e : 0.2f * e);
}

// fill CSR slots: single 8B store per edge {src, bf16 w0 | w1<<16}; no atomics
__global__ __launch_bounds__(256) void fillw_kernel(
    const int* __restrict__ esrc, const int* __restrict__ edst,
    const int* __restrict__ rank, const int* __restrict__ rowptr,
    uint2* __restrict__ eslot,
    const float* __restrict__ a_s, const float* __restrict__ a_d, int E, int N)
{
    int e = blockIdx.x * 256 + threadIdx.x;
    if (e < E) {
        int src = esrc[e], dst = edst[e];
        int pos = rowptr[dst] + 1 + rank[e];
        float2 as = *(const float2*)(a_s + 2 * src);
        float2 ad = *(const float2*)(a_d + 2 * dst);
        unsigned int w0 = f2b(edge_w(as.x + ad.x));
        unsigned int w1 = f2b(edge_w(as.y + ad.y));
        uint2 o; o.x = (unsigned int)src; o.y = (w1 << 16) | w0;
        eslot[pos] = o;
    } else if (e < E + N) {
        int v = e - E;
        float2 as = *(const float2*)(a_s + 2 * v);
        float2 ad = *(const float2*)(a_d + 2 * v);
        unsigned int w0 = f2b(edge_w(as.x + ad.x));
        unsigned int w1 = f2b(edge_w(as.y + ad.y));
        uint2 o; o.x = (unsigned int)v; o.y = (w1 << 16) | w0;
        eslot[rowptr[v]] = o;
    }
}

// ---------------- layer-1 gather: 1 WAVE/node (4 nodes/block), 2 slots x 32 lanes(x4 dims) ----------------
template<int B>
__device__ __forceinline__ void gat1_batch(
    int i0, int end, int endm1, int wsh,
    const uint2* __restrict__ eslot, const uint2* __restrict__ h1u, unsigned int dp,
    float& a0, float& a1, float& a2, float& a3, float& den)
{
    int ics[B];
    uint2 sl[B];
    float wv[B];
    uint2 hv[B];
    #pragma unroll
    for (int k = 0; k < B; k++) ics[k] = min(i0 + 2 * k, endm1);
    #pragma unroll
    for (int k = 0; k < B; k++) sl[k] = eslot[ics[k]];
    #pragma unroll
    for (int k = 0; k < B; k++) {
        float w = u2f((sl[k].y << wsh) & 0xffff0000u);
        wv[k] = (i0 + 2 * k < end) ? w : 0.f;
    }
    #pragma unroll
    for (int k = 0; k < B; k++) hv[k] = h1u[(sl[k].x << 5) | dp];
    #pragma unroll
    for (int k = 0; k < B; k++) {
        float w = wv[k];
        den += w;
        a0 = fmaf(w, u2f(hv[k].x << 16),          a0);
        a1 = fmaf(w, u2f(hv[k].x & 0xffff0000u),  a1);
        a2 = fmaf(w, u2f(hv[k].y << 16),          a2);
        a3 = fmaf(w, u2f(hv[k].y & 0xffff0000u),  a3);
    }
}

__global__ __launch_bounds__(256) void gat1_gather_kernel(
    const int* __restrict__ rowptr, const uint2* __restrict__ eslot,
    const uint2* __restrict__ h1u,
    const float* __restrict__ b1, uint2* __restrict__ g1b, int N)
{
    const int v = blockIdx.x * 4 + (threadIdx.x >> 6);
    if (v >= N) return;
    const int lane = threadIdx.x & 63;
    const int slot = lane >> 5;
    const unsigned int dp = lane & 31;
    const int head = dp >> 4;
    const int wsh = head ? 0 : 16;
    const int beg = rowptr[v], end = rowptr[v + 1];
    const int deg = end - beg;
    const int endm1 = end - 1;
    const int i0 = beg + slot;

    float a0 = 0.f, a1 = 0.f, a2 = 0.f, a3 = 0.f, den = 0.f;

    if (deg <= 8) {
        gat1_batch<4>(i0, end, endm1, wsh, eslot, h1u, dp, a0, a1, a2, a3, den);
    } else {
        gat1_batch<8>(i0, end, endm1, wsh, eslot, h1u, dp, a0, a1, a2, a3, den);
        for (int base = i0 + 16; base < end; base += 8)
            gat1_batch<4>(base, end, endm1, wsh, eslot, h1u, dp, a0, a1, a2, a3, den);
    }

    a0 += __shfl_xor(a0, 32, 64);
    a1 += __shfl_xor(a1, 32, 64);
    a2 += __shfl_xor(a2, 32, 64);
    a3 += __shfl_xor(a3, 32, 64);
    den += __shfl_xor(den, 32, 64);

    if (lane < 32) {
        float inv = 1.f / (den + 1e-16f);
        float4 bv = *(const float4*)(b1 + 4 * dp);
        float o0 = fmaxf(fmaf(a0, inv, bv.x), 0.f);
        float o1 = fmaxf(fmaf(a1, inv, bv.y), 0.f);
        float o2 = fmaxf(fmaf(a2, inv, bv.z), 0.f);
        float o3 = fmaxf(fmaf(a3, inv, bv.w), 0.f);
        uint2 o;
        o.x = ((unsigned int)f2b(o1) << 16) | f2b(o0);
        o.y = ((unsigned int)f2b(o3) << 16) | f2b(o2);
        g1b[((unsigned int)v << 5) | dp] = o;
    }
}

// ---------------- gat2 projection (MFMA): h2 = g1b @ W2; fused a_s2/a_d2 ----------------
__global__ __launch_bounds__(256) void gat2_proj_kernel(
    const unsigned short* __restrict__ g1b, const short* __restrict__ w2t,
    const float* __restrict__ as2w, const float* __restrict__ ad2w,
    float* __restrict__ h2, float* __restrict__ a_s2, float* __restrict__ a_d2, int N)
{
    const int tid = threadIdx.x;
    const int wave = tid >> 6, lane = tid & 63;
    const int q = lane >> 4, col = lane & 15;
    const int mb = blockIdx.x * 64 + wave * 16;
    const int arow = min(mb + col, N - 1);
    const short* ap = (const short*)g1b + (size_t)arow * 128 + q * 8;
    const short* bp = w2t + (size_t)col * 128 + q * 8;

    f32x4 acc = {0.f, 0.f, 0.f, 0.f};
    #pragma unroll
    for (int ks = 0; ks < 4; ks++)
        acc = __builtin_amdgcn_mfma_f32_16x16x32_bf16(
            *(const bf16x8*)(ap + ks * 32), *(const bf16x8*)(bp + ks * 32), acc, 0, 0, 0);

    const float asj = as2w[col], adj = ad2w[col];
    #pragma unroll
    for (int i = 0; i < 4; i++) {
        int row = mb + q * 4 + i;
        float ps = acc[i] * asj, pd = acc[i] * adj;
        #pragma unroll
        for (int off = 1; off < 16; off <<= 1) {
            ps += __shfl_xor(ps, off, 16);
            pd += __shfl_xor(pd, off, 16);
        }
        if (row < N) {
            h2[(size_t)row * 16 + col] = acc[i];
            if (col == 0) { a_s2[row] = ps; a_d2[row] = pd; }
        }
    }
}

// ---------------- fused layer-2 gather + head (4 masked nodes/block) ----------------
__global__ __launch_bounds__(256) void gat2_final_kernel(
    const int* __restrict__ rowptr, const uint2* __restrict__ eslot,
    const float* __restrict__ h2,
    const float* __restrict__ a_s2, const float* __restrict__ a_d2,
    const float* __restrict__ b2, const int* __restrict__ mask,
    const float* __restrict__ text_out,
    const float* __restrict__ fcf_w, const float* __restrict__ fcf_b,
    float* __restrict__ out, int M)
{
    const int tid = threadIdx.x;
    const int m = blockIdx.x * 4 + (tid >> 6);
    if (m >= M) return;
    const int lane = tid & 63, slot = lane >> 4, c = lane & 15;
    const int v = mask[m];
    const float adv = a_d2[v];
    const int beg = rowptr[v], end = rowptr[v + 1];
    const int i0 = beg + slot;

    float acc = 0.f, den = 0.f;
    unsigned int idxs[8];
    float msk[8], as_[8], hval[8];
    #pragma unroll
    for (int k = 0; k < 8; k++) {
        int i = i0 + 4 * k;
        int ic = min(i, end - 1);
        idxs[k] = eslot[ic].x;
        msk[k] = (i < end) ? 1.f : 0.f;
    }
    #pragma unroll
    for (int k = 0; k < 8; k++) as_[k] = a_s2[idxs[k]];
    #pragma unroll
    for (int k = 0; k < 8; k++) hval[k] = h2[(idxs[k] << 4) | (unsigned)c];
    #pragma unroll
    for (int k = 0; k < 8; k++) {
        float e = as_[k] + adv;
        float w = msk[k] * __expf(e > 0.f ? e : 0.2f * e);
        den += w;
        acc = fmaf(w, hval[k], acc);
    }
    for (int i = i0 + 32; i < end; i += 4) {
        unsigned int src = eslot[i].x;
        float e = a_s2[src] + adv;
        float w = __expf(e > 0.f ? e : 0.2f * e);
        den += w;
        acc = fmaf(w, h2[(src << 4) | (unsigned)c], acc);
    }

    acc += __shfl_xor(acc, 16, 64);
    acc += __shfl_xor(acc, 32, 64);
    den += __shfl_xor(den, 16, 64);
    den += __shfl_xor(den, 32, 64);

    if (slot == 0) {
        float gval = acc / (den + 1e-16f) + b2[c];
        float tval = text_out[(size_t)m * 16 + c];

        float logit = fcf_b[c];
        #pragma unroll
        for (int k = 0; k < 16; k++) {
            logit = fmaf(__shfl(tval, k, 16), fcf_w[k * 16 + c], logit);
            logit = fmaf(__shfl(gval, k, 16), fcf_w[(16 + k) * 16 + c], logit);
        }
        float mx = logit;
        #pragma unroll
        for (int off = 8; off > 0; off >>= 1) mx = fmaxf(mx, __shfl_xor(mx, off, 16));
        float se = expf(logit - mx);
        #pragma unroll
        for (int off = 8; off > 0; off >>= 1) se += __shfl_xor(se, off, 16);
        out[(size_t)m * 16 + c] = logit - mx - logf(se);
    }
}

extern "C" void kernel_launch(void* const* d_in, const int* in_sizes, int n_in,
                              void* d_out, int out_size, void* d_ws, size_t ws_size,
                              hipStream_t stream)
{
    const float* text  = (const float*)d_in[0];
    const float* x     = (const float*)d_in[1];
    const int*   ei    = (const int*)  d_in[2];
    const int*   mask  = (const int*)  d_in[3];
    const float* fc1_w = (const float*)d_in[4];  const float* fc1_b = (const float*)d_in[5];
    const float* fc2_w = (const float*)d_in[6];  const float* fc2_b = (const float*)d_in[7];
    const float* fc3_w = (const float*)d_in[8];  const float* fc3_b = (const float*)d_in[9];
    const float* fc4_w = (const float*)d_in[10]; const float* fc4_b = (const float*)d_in[11];
    const float* sc_w  = (const float*)d_in[12]; const float* sc_b  = (const float*)d_in[13];
    const float* W1    = (const float*)d_in[14];
    const float* as1w  = (const float*)d_in[15]; const float* ad1w  = (const float*)d_in[16];
    const float* b1    = (const float*)d_in[17];
    const float* W2    = (const float*)d_in[18];
    const float* as2w  = (const float*)d_in[19]; const float* ad2w  = (const float*)d_in[20];
    const float* b2    = (const float*)d_in[21];
    const float* fcf_w = (const float*)d_in[22]; const float* fcf_b = (const float*)d_in[23];

    const int M  = in_sizes[3];
    const int N  = in_sizes[1] / GNN_DIM;
    const int E  = in_sizes[2] / 2;
    const int EP = E + N;
    const int* esrc = ei;
    const int* edst = ei + E;

    const int Np = ((N + 63) / 64) * 64;
    const int NB = (N + 255) / 256;        // <= 256

    float* ws = (float*)d_ws;
    size_t off = 0;
    auto alloc = [&](size_t n) { float* p = ws + off; off += (n + 63) & ~size_t(63); return p; };

    unsigned short* h1    = (unsigned short*)alloc((size_t)Np * 64);   // bf16 [Np x 128]
    unsigned int*   g1b   = (unsigned int*)  alloc((size_t)N * 64);    // bf16 [N x 128] packed
    unsigned short* w1cat = (unsigned short*)alloc(144 * 256);         // bf16 [144 x 512]
    unsigned short* w1g   = (unsigned short*)alloc(128 * 64);          // bf16 [128 x 128]
    unsigned short* w2t   = (unsigned short*)alloc(16 * 64);           // bf16 [16 x 128]
    unsigned short* fc2t  = (unsigned short*)alloc(64 * 64);           // bf16 [64 x 128]
    unsigned short* fc3t  = (unsigned short*)alloc(16 * 32);           // bf16 [16 x 64]
    unsigned short* fc4t  = (unsigned short*)alloc(16 * 16);           // bf16 [16 x 32]
    float* a_s1     = alloc((size_t)2 * N);
    float* a_d1     = alloc((size_t)2 * N);
    float* h2       = alloc((size_t)N * 16);
    float* a_s2     = alloc(N);
    float* a_d2     = alloc(N);
    float* text_out = alloc((size_t)M * 16);
    uint2* eslot    = (uint2*)alloc((size_t)2 * EP);   // {src, bf16w0|bf16w1<<16}
    int* deg        = (int*)alloc((size_t)N * 32);     // padded: 1 counter / 128B
    int* rank       = (int*)alloc(E);
    int* rowptr     = (int*)alloc(N + 1);
    int* bsum       = (int*)alloc(256);

    const int convBlocks = (101888 + 255) / 256;

    // --- setup: zero counters + all weights to bf16 (one kernel) ---
    setup_kernel<<<NB + convBlocks, 256, 0, stream>>>(
        deg, N, NB, fc1_w, sc_w, W1, W2, fc2_w, fc3_w, fc4_w,
        w1cat, w1g, w2t, fc2t, fc3t, fc4t);

    // --- CSR: histogram(+rank) -> part sums -> rowptr (inline bsum scan) ---
    deg_hist_kernel<<<(E + 1023) / 1024, 256, 0, stream>>>(edst, deg, rank, E);
    part_kernel<<<NB, 256, 0, stream>>>(deg, bsum, N);
    rowptr_kernel<<<NB, 256, 0, stream>>>(deg, bsum, rowptr, N, NB);

    // --- GAT1 projection (produces a_s1/a_d1 for weight fill) ---
    gemm_h1_kernel<<<Np / 64, 256, 0, stream>>>(
        x, (const short*)w1g, as1w, ad1w, h1, a_s1, a_d1, N);

    // --- CSR fill: single 8B slot per edge, no atomics ---
    fillw_kernel<<<(E + N + 255) / 256, 256, 0, stream>>>(
        esrc, edst, rank, rowptr, eslot, a_s1, a_d1, E, N);

    // --- text branch: fully-MFMA, K-split-4, 4 waves / 16-row tile ---
    text_mfma_kernel<<<(M + 15) / 16, 256, 0, stream>>>(
        text, (const short*)w1cat, fc1_b, sc_b,
        (const short*)fc2t, fc2_b, (const short*)fc3t, fc3_b,
        (const short*)fc4t, fc4_b, text_out, M);

    // --- GNN aggregation / second layer ---
    gat1_gather_kernel<<<(N + 3) / 4, 256, 0, stream>>>(
        rowptr, eslot, (const uint2*)h1, b1, (uint2*)g1b, N);

    gat2_proj_kernel<<<Np / 64, 256, 0, stream>>>(
        (const unsigned short*)g1b, (const short*)w2t, as2w, ad2w, h2, a_s2, a_d2, N);

    // --- fused layer-2 gather + head ---
    gat2_final_kernel<<<(M + 3) / 4, 256, 0, stream>>>(
        rowptr, eslot, h2, a_s2, a_d2, b2, mask, text_out, fcf_w, fcf_b,
        (float*)d_out, M);
}